// Round 15
// baseline (52.659 us; speedup 1.0000x reference)
//
#include <hip/hip_runtime.h>

#define SENT    256
#define BATCH   64
#define WLEN    16
#define D_WORDE 300
#define D_CHARE 50
#define OUT_CH  200
#define KSIZE   3
#define NPOS    14
#define D_OUT   500
#define NWORDS  (SENT * BATCH)

// GEMM geometry: M=16 positions/word, N=13x16=208, K=3*64=192 (kg=kk*64+c)
// Bias folded into K: charP col63 = 1.0, WO[o][191] = conv_b[o]  (max(y+b)=max(y)+b)
#define KPAD      192
#define MPAD      208
#define CHARP_U16 (129 * 64)
#define WO_U16    (MPAD * KPAD)
#define WS_NEED   ((size_t)(CHARP_U16 + WO_U16) * 2)

#define WPB         16                 // words per conv block (2 halves of 8)
#define HALF_U16    8192               // 8 words * 16 rows * 64 cols
#define TILE_TOT    (2 * HALF_U16 + 128)  // + 2 slack rows for last word's taps
#define CONV_BLOCKS (NWORDS / WPB)     // 1024
#define EMB_BLOCKS  (NWORDS / 4)       // 4096
#define GRID        (CONV_BLOCKS + EMB_BLOCKS)   // 5120; conv when blockIdx%5==0

typedef short  short8  __attribute__((ext_vector_type(8)));
typedef ushort ushort8 __attribute__((ext_vector_type(8)));
typedef float  float4v __attribute__((ext_vector_type(4)));

// direct global->LDS (16B/lane, dest = wave-uniform base + lane*16; src per-lane)
#define GLOAD16(SRC, DST)                                                     \
    __builtin_amdgcn_global_load_lds(                                         \
        (const __attribute__((address_space(1))) void*)(SRC),                 \
        (__attribute__((address_space(3))) void*)(DST), 16, 0, 0)

__device__ __forceinline__ ushort f2bf(float f) {
    unsigned u = __float_as_uint(f);
    u = (u + 0x7FFFu + ((u >> 16) & 1u)) >> 16;   // RNE
    return (ushort)u;
}

// ---------- prep: bf16 char table (col63=1.0) + K-major weights (kg191=bias) ----------
__global__ void prep_kernel(const float* __restrict__ W_char,
                            const float* __restrict__ conv_w,
                            const float* __restrict__ conv_b,
                            ushort* __restrict__ ws) {
    int j = blockIdx.x * 256 + threadIdx.x;
    if (j < CHARP_U16) {
        int r = j >> 6, c = j & 63;
        ushort v = 0;
        if (r < 128) {
            if (c < D_CHARE)      v = f2bf(W_char[r * D_CHARE + c]);
            else if (c == 63)     v = 0x3F80;        // 1.0 bf16 (bias lane)
        }
        ws[j] = v;
    }
    int j2 = j - CHARP_U16;
    if (j2 >= 0 && j2 < WO_U16) {
        int o = j2 / KPAD, kg = j2 - o * KPAD;
        int kk = kg >> 6, c = kg & 63;
        float v = 0.f;
        if (o < OUT_CH) {
            if (c < D_CHARE)      v = conv_w[o * (D_CHARE * KSIZE) + c * KSIZE + kk];
            else if (kg == 191)   v = conv_b[o];     // bias rides K-slot 191
        }
        ws[CHARP_U16 + j2] = f2bf(v);
    }
}

__device__ __forceinline__ float redmax14(float4v d, int lg) {
    float m01 = fmaxf(d[0], d[1]);
    float m23 = fmaxf(d[2], d[3]);
    float m = (lg == 3) ? m01 : fmaxf(m01, m23);   // rows 14,15 excluded (garbage-safe)
    m = fmaxf(m, __shfl_xor(m, 16, 64));
    m = fmaxf(m, __shfl_xor(m, 32, 64));
    return m;
}

// ---------- fused grid: conv (%5==0, 2-phase, t12 folded in-phase) + emb copy ----------
// NO __launch_bounds__ min-waves (r5/r6/r8: force-occupancy => spill/wave cliff).
__global__ void __launch_bounds__(256)
fused_kernel(const int* __restrict__ words, const int* __restrict__ chars,
             const float* __restrict__ W_word, const ushort* __restrict__ ws,
             float* __restrict__ out) {
    __shared__ __align__(16) ushort tile[TILE_TOT];   // ~33 KB

    const int tid  = threadIdx.x;
    const int lane = tid & 63;
    const int wave = tid >> 6;

    if (blockIdx.x % 5 != 0) {
        // ---- word embedding: one wave per output row, float4 copy (proven)
        const int eb = blockIdx.x - blockIdx.x / 5 - 1;       // 0..4095
        const int m  = eb * 4 + wave;
        const int idx = words[m];
        const float4v* __restrict__ src = (const float4v*)(W_word + (size_t)idx * D_WORDE);
        float4v* __restrict__ dst = (float4v*)(out + (size_t)m * D_OUT);
        dst[lane] = src[lane];                                 // 75 float4 per row
        if (lane < 75 - 64) dst[64 + lane] = src[64 + lane];
        return;
    }

    const ushort* __restrict__ charP = ws;
    const ushort* __restrict__ WO    = ws + CHARP_U16;
    const int block0 = (blockIdx.x / 5) * WPB;
    const int l15 = lane & 15;
    const int lg  = lane >> 4;
    const int srcblk = (lane & 7) ^ ((lane >> 3) & 7);   // pre-swizzled source block

    // ---- ids prefetch for BOTH halves (wave stages words {wave*2, wave*2+1}/half)
    int ids[2][2][2];
    #pragma unroll
    for (int h = 0; h < 2; h++)
        #pragma unroll
        for (int ww = 0; ww < 2; ww++) {
            const int m = block0 + h * 8 + wave * 2 + ww;
            const int* __restrict__ cbase = chars + ((m & 63) * SENT + (m >> 6)) * WLEN;
            #pragma unroll
            for (int s = 0; s < 2; s++)
                ids[h][ww][s] = cbase[s * 8 + (lane >> 3)];
        }

    // ---- B fragments (latency hides under staging); bias inside K
    short8 B[3][6];
    #pragma unroll
    for (int i = 0; i < 3; i++) {
        int col = (wave + 4 * i) * 16 + l15;                  // <= 191
        #pragma unroll
        for (int s = 0; s < 6; s++)
            B[i][s] = *(const short8*)&WO[col * KPAD + s * 32 + lg * 8];
    }
    // tile-12 fragments (channels 192..199), folded into phase 1 rounds
    short8 B12[6];
    #pragma unroll
    for (int s = 0; s < 6; s++)
        B12[s] = *(const short8*)&WO[(192 + l15) * KPAD + s * 32 + lg * 8];

#define STAGE_HALF(h)                                                         \
    {                                                                         \
        _Pragma("unroll")                                                     \
        for (int ww = 0; ww < 2; ww++) {                                      \
            const int wl = (h) * 8 + wave * 2 + ww;                           \
            _Pragma("unroll")                                                 \
            for (int s = 0; s < 2; s++) {                                     \
                const ushort* src_ = charP + ids[h][ww][s] * 64 + (srcblk << 3); \
                GLOAD16(src_, &tile[wl * 1024 + s * 512]);                    \
            }                                                                 \
        }                                                                     \
    }

    // ---- loop-invariant swizzled LDS read offsets; word stride 1024 u16
    int offA[6];
    #pragma unroll
    for (int s = 0; s < 6; s++) {
        int l  = l15 + (s >> 1);
        int bb = (((s & 1) * 4 + lg) ^ (l & 7));
        offA[s] = l * 64 + (bb << 3);
    }

#define PHASE1_HALF(h)                                                        \
    _Pragma("unroll 1")                                                       \
    for (int r = (h) * 8; r < (h) * 8 + 8; r++) {                             \
        const int base = r << 10;                                             \
        short8 a[6];                                                          \
        _Pragma("unroll")                                                     \
        for (int s = 0; s < 6; s++)                                           \
            a[s] = *(const short8*)&tile[base + offA[s]];                     \
        float4v acc[3];                                                       \
        _Pragma("unroll")                                                     \
        for (int i = 0; i < 3; i++) acc[i] = (float4v){0, 0, 0, 0};           \
        const bool do12 = ((r & 3) == wave);                                  \
        float4v acc12 = (float4v){0, 0, 0, 0};                                \
        __builtin_amdgcn_s_setprio(1);                                        \
        _Pragma("unroll")                                                     \
        for (int s = 0; s < 6; s++) {                                         \
            _Pragma("unroll")                                                 \
            for (int i = 0; i < 3; i++)                                       \
                acc[i] = __builtin_amdgcn_mfma_f32_16x16x32_bf16(             \
                    a[s], B[i][s], acc[i], 0, 0, 0);                          \
            if (do12)                                                         \
                acc12 = __builtin_amdgcn_mfma_f32_16x16x32_bf16(              \
                    a[s], B12[s], acc12, 0, 0, 0);                            \
        }                                                                     \
        __builtin_amdgcn_s_setprio(0);                                        \
        float* obase = out + (size_t)(block0 + r) * D_OUT + D_WORDE;          \
        _Pragma("unroll")                                                     \
        for (int i = 0; i < 3; i++) {                                         \
            float mx = redmax14(acc[i], lg);                                  \
            if (lane < 16) obase[(wave + 4 * i) * 16 + lane] = mx;            \
        }                                                                     \
        if (do12) {                                                           \
            float mx12 = redmax14(acc12, lg);                                 \
            if (lane < 8) obase[192 + lane] = mx12;                           \
        }                                                                     \
    }

    // ---- 2-phase pipeline: stage0 | bar | stage1-issue, compute0 | bar | compute1
    STAGE_HALF(0)
    __syncthreads();                       // drains stage0 (vmcnt0 + barrier)
    STAGE_HALF(1)                          // flies under compute of half 0
    PHASE1_HALF(0)
    __syncthreads();                       // drains stage1
    PHASE1_HALF(1)
#undef STAGE_HALF
#undef PHASE1_HALF
}

// ---------- fallbacks (tiny ws): round-1 proven kernels ----------
__global__ void __launch_bounds__(256)
word_emb_kernel(const int* __restrict__ words, const float* __restrict__ W_word,
                float* __restrict__ out) {
    int wave = threadIdx.x >> 6, lane = threadIdx.x & 63;
    int m = blockIdx.x * 4 + wave;
    int idx = words[m];
    const float* __restrict__ src = W_word + (size_t)idx * D_WORDE;
    float* __restrict__ dst = out + (size_t)m * D_OUT;
    for (int j = lane; j < D_WORDE; j += 64) dst[j] = src[j];
}

__global__ void __launch_bounds__(256)
char_conv_f32_kernel(const int* __restrict__ chars, const float* __restrict__ W_char,
                     const float* __restrict__ conv_w, const float* __restrict__ conv_b,
                     float* __restrict__ out) {
    __shared__ __align__(16) float xs[D_CHARE * WLEN];
    __shared__ int ids[WLEN];
    int m = blockIdx.x, s = m >> 6, b = m & 63, tid = threadIdx.x;
    if (tid < WLEN) ids[tid] = chars[(b * SENT + s) * WLEN + tid];
    __syncthreads();
    for (int e = tid; e < D_CHARE * WLEN; e += 256) {
        int c = e >> 4, l = e & 15;
        xs[e] = W_char[ids[l] * D_CHARE + c];
    }
    __syncthreads();
    if (tid < OUT_CH) {
        float acc[NPOS];
        #pragma unroll
        for (int p = 0; p < NPOS; p++) acc[p] = 0.f;
        const float4* xs4 = (const float4*)xs;
        for (int c = 0; c < D_CHARE; c++) {
            float4 a0 = xs4[c*4+0], a1 = xs4[c*4+1], a2 = xs4[c*4+2], a3 = xs4[c*4+3];
            float xr[WLEN] = {a0.x,a0.y,a0.z,a0.w, a1.x,a1.y,a1.z,a1.w,
                              a2.x,a2.y,a2.z,a2.w, a3.x,a3.y,a3.z,a3.w};
            #pragma unroll
            for (int k = 0; k < KSIZE; k++) {
                float wv = conv_w[tid * (D_CHARE * KSIZE) + c * KSIZE + k];
                #pragma unroll
                for (int p = 0; p < NPOS; p++) acc[p] = fmaf(wv, xr[p + k], acc[p]);
            }
        }
        float mx = acc[0];
        #pragma unroll
        for (int p = 1; p < NPOS; p++) mx = fmaxf(mx, acc[p]);
        out[(size_t)m * D_OUT + D_WORDE + tid] = mx + conv_b[tid];
    }
}

extern "C" void kernel_launch(void* const* d_in, const int* in_sizes, int n_in,
                              void* d_out, int out_size, void* d_ws, size_t ws_size,
                              hipStream_t stream) {
    const int*   words  = (const int*)d_in[0];
    const int*   chars  = (const int*)d_in[1];
    const float* W_word = (const float*)d_in[2];
    const float* W_char = (const float*)d_in[3];
    const float* conv_w = (const float*)d_in[4];
    const float* conv_b = (const float*)d_in[5];
    float* out = (float*)d_out;

    if (ws_size >= WS_NEED) {
        ushort* ws = (ushort*)d_ws;
        hipLaunchKernelGGL(prep_kernel,
                           dim3((CHARP_U16 + WO_U16 + 255) / 256), dim3(256), 0, stream,
                           W_char, conv_w, conv_b, ws);
        hipLaunchKernelGGL(fused_kernel, dim3(GRID), dim3(256), 0, stream,
                           words, chars, W_word, ws, out);
    } else {
        hipLaunchKernelGGL(word_emb_kernel, dim3(NWORDS / 4), dim3(256), 0, stream,
                           words, W_word, out);
        hipLaunchKernelGGL(char_conv_f32_kernel, dim3(NWORDS), dim3(256), 0, stream,
                           chars, W_char, conv_w, conv_b, out);
    }
}

// Round 16
// 45.535 us; speedup vs baseline: 1.1564x; 1.1564x over previous
//
#include <hip/hip_runtime.h>

#define SENT    256
#define BATCH   64
#define WLEN    16
#define D_WORDE 300
#define D_CHARE 50
#define OUT_CH  200
#define KSIZE   3
#define NPOS    14
#define D_OUT   500
#define NWORDS  (SENT * BATCH)

// GEMM geometry: M=16 positions/word, N=13x16=208, K=3*64=192 (kg=kk*64+c)
// Bias folded into K: charP col63 = 1.0, WO[o][191] = conv_b[o]  (max(y+b)=max(y)+b)
#define KPAD      192
#define MPAD      208
#define CHARP_U16 (129 * 64)
#define WO_U16    (MPAD * KPAD)
#define WS_NEED   ((size_t)(CHARP_U16 + WO_U16) * 2)

#define WPB         16                 // words per conv block (2 halves of 8)
#define HALF_U16    8192               // 8 words * 16 rows * 64 cols
#define TILE_TOT    (2 * HALF_U16 + 128)  // + 2 slack rows for last word's taps
#define CONV_BLOCKS (NWORDS / WPB)     // 1024 uniform blocks (emb folded in)

typedef short  short8  __attribute__((ext_vector_type(8)));
typedef ushort ushort8 __attribute__((ext_vector_type(8)));
typedef float  float4v __attribute__((ext_vector_type(4)));

// direct global->LDS (16B/lane, dest = wave-uniform base + lane*16; src per-lane)
#define GLOAD16(SRC, DST)                                                     \
    __builtin_amdgcn_global_load_lds(                                         \
        (const __attribute__((address_space(1))) void*)(SRC),                 \
        (__attribute__((address_space(3))) void*)(DST), 16, 0, 0)

__device__ __forceinline__ ushort f2bf(float f) {
    unsigned u = __float_as_uint(f);
    u = (u + 0x7FFFu + ((u >> 16) & 1u)) >> 16;   // RNE
    return (ushort)u;
}

// ---------- prep: bf16 char table (col63=1.0) + K-major weights (kg191=bias) ----------
__global__ void prep_kernel(const float* __restrict__ W_char,
                            const float* __restrict__ conv_w,
                            const float* __restrict__ conv_b,
                            ushort* __restrict__ ws) {
    int j = blockIdx.x * 256 + threadIdx.x;
    if (j < CHARP_U16) {
        int r = j >> 6, c = j & 63;
        ushort v = 0;
        if (r < 128) {
            if (c < D_CHARE)      v = f2bf(W_char[r * D_CHARE + c]);
            else if (c == 63)     v = 0x3F80;        // 1.0 bf16 (bias lane)
        }
        ws[j] = v;
    }
    int j2 = j - CHARP_U16;
    if (j2 >= 0 && j2 < WO_U16) {
        int o = j2 / KPAD, kg = j2 - o * KPAD;
        int kk = kg >> 6, c = kg & 63;
        float v = 0.f;
        if (o < OUT_CH) {
            if (c < D_CHARE)      v = conv_w[o * (D_CHARE * KSIZE) + c * KSIZE + kk];
            else if (kg == 191)   v = conv_b[o];     // bias rides K-slot 191
        }
        ws[CHARP_U16 + j2] = f2bf(v);
    }
}

__device__ __forceinline__ float redmax14(float4v d, int lg) {
    float m01 = fmaxf(d[0], d[1]);
    float m23 = fmaxf(d[2], d[3]);
    float m = (lg == 3) ? m01 : fmaxf(m01, m23);   // rows 14,15 excluded (garbage-safe)
    m = fmaxf(m, __shfl_xor(m, 16, 64));
    m = fmaxf(m, __shfl_xor(m, 32, 64));
    return m;
}

// ---------- uniform block: 2-phase conv + emb (issue-early / write-late) ----------
// NO __launch_bounds__ min-waves (r5/r6/r8: force-occupancy => spill/wave cliff).
__global__ void __launch_bounds__(256)
fused_kernel(const int* __restrict__ words, const int* __restrict__ chars,
             const float* __restrict__ W_word, const ushort* __restrict__ ws,
             float* __restrict__ out) {
    __shared__ __align__(16) ushort tile[TILE_TOT];   // ~33 KB -> 4 blocks/CU (LDS-bound)

    const int tid  = threadIdx.x;
    const int lane = tid & 63;
    const int wave = tid >> 6;

    const ushort* __restrict__ charP = ws;
    const ushort* __restrict__ WO    = ws + CHARP_U16;
    const int block0 = blockIdx.x * WPB;
    const int l15 = lane & 15;
    const int lg  = lane >> 4;
    const int srcblk = (lane & 7) ^ ((lane >> 3) & 7);   // pre-swizzled source block

    // ---- T14 issue-early: this wave's 4 word-emb rows -> registers.
    // Independent of everything below; HBM latency hides under staging + 2 MFMA phases.
    const int me = block0 + wave * 4;
    const bool tail = lane < (75 - 64);
    float4v e0[4], e1[4];
    #pragma unroll
    for (int r = 0; r < 4; r++) {
        const float4v* __restrict__ src =
            (const float4v*)(W_word + (size_t)words[me + r] * D_WORDE);
        e0[r] = src[lane];
        e1[r] = tail ? src[64 + lane] : (float4v){0, 0, 0, 0};
    }

    // ---- ids prefetch for BOTH halves (wave stages words {wave*2, wave*2+1}/half)
    int ids[2][2][2];
    #pragma unroll
    for (int h = 0; h < 2; h++)
        #pragma unroll
        for (int ww = 0; ww < 2; ww++) {
            const int m = block0 + h * 8 + wave * 2 + ww;
            const int* __restrict__ cbase = chars + ((m & 63) * SENT + (m >> 6)) * WLEN;
            #pragma unroll
            for (int s = 0; s < 2; s++)
                ids[h][ww][s] = cbase[s * 8 + (lane >> 3)];
        }

    // ---- B fragments (latency hides under staging); bias inside K
    short8 B[3][6];
    #pragma unroll
    for (int i = 0; i < 3; i++) {
        int col = (wave + 4 * i) * 16 + l15;                  // <= 191
        #pragma unroll
        for (int s = 0; s < 6; s++)
            B[i][s] = *(const short8*)&WO[col * KPAD + s * 32 + lg * 8];
    }

#define STAGE_HALF(h)                                                         \
    {                                                                         \
        _Pragma("unroll")                                                     \
        for (int ww = 0; ww < 2; ww++) {                                      \
            const int wl = (h) * 8 + wave * 2 + ww;                           \
            _Pragma("unroll")                                                 \
            for (int s = 0; s < 2; s++) {                                     \
                const ushort* src_ = charP + ids[h][ww][s] * 64 + (srcblk << 3); \
                GLOAD16(src_, &tile[wl * 1024 + s * 512]);                    \
            }                                                                 \
        }                                                                     \
    }

    // ---- loop-invariant swizzled LDS read offsets; word stride 1024 u16
    int offA[6];
    #pragma unroll
    for (int s = 0; s < 6; s++) {
        int l  = l15 + (s >> 1);
        int bb = (((s & 1) * 4 + lg) ^ (l & 7));
        offA[s] = l * 64 + (bb << 3);
    }

#define PHASE1_HALF(h)                                                        \
    _Pragma("unroll 1")                                                       \
    for (int r = (h) * 8; r < (h) * 8 + 8; r++) {                             \
        const int base = r << 10;                                             \
        short8 a[6];                                                          \
        _Pragma("unroll")                                                     \
        for (int s = 0; s < 6; s++)                                           \
            a[s] = *(const short8*)&tile[base + offA[s]];                     \
        float4v acc[3];                                                       \
        _Pragma("unroll")                                                     \
        for (int i = 0; i < 3; i++) acc[i] = (float4v){0, 0, 0, 0};           \
        _Pragma("unroll")                                                     \
        for (int s = 0; s < 6; s++)                                           \
            _Pragma("unroll")                                                 \
            for (int i = 0; i < 3; i++)                                       \
                acc[i] = __builtin_amdgcn_mfma_f32_16x16x32_bf16(             \
                    a[s], B[i][s], acc[i], 0, 0, 0);                          \
        float* obase = out + (size_t)(block0 + r) * D_OUT + D_WORDE;          \
        _Pragma("unroll")                                                     \
        for (int i = 0; i < 3; i++) {                                         \
            float mx = redmax14(acc[i], lg);                                  \
            if (lane < 16) obase[(wave + 4 * i) * 16 + lane] = mx;            \
        }                                                                     \
    }

    // ---- 2-phase pipeline: stage0 | bar | stage1-issue, compute0 | bar | compute1
    STAGE_HALF(0)
    __syncthreads();                       // drains stage0 (vmcnt0 + barrier)
    STAGE_HALF(1)                          // flies under compute of half 0
    PHASE1_HALF(0)
    __syncthreads();                       // drains stage1
    PHASE1_HALF(1)

    // ---- phase 2: tile 12 (channels 192..199); wave does 4 words (both bufs valid)
    {
        short8 B12[6];
        #pragma unroll
        for (int s = 0; s < 6; s++)
            B12[s] = *(const short8*)&WO[(192 + l15) * KPAD + s * 32 + lg * 8];

        #pragma unroll 1
        for (int r2 = 0; r2 < 4; r2++) {
            const int widx = wave * 4 + r2;
            const int base = widx << 10;
            short8 a[6];
            #pragma unroll
            for (int s = 0; s < 6; s++)
                a[s] = *(const short8*)&tile[base + offA[s]];
            float4v acc = {0, 0, 0, 0};
            #pragma unroll
            for (int s = 0; s < 6; s++)
                acc = __builtin_amdgcn_mfma_f32_16x16x32_bf16(a[s], B12[s], acc, 0, 0, 0);
            float mx = redmax14(acc, lg);
            if (lane < 8)
                out[(size_t)(block0 + widx) * D_OUT + D_WORDE + 192 + lane] = mx;
        }
    }

    // ---- T14 write-late: emb rows from registers
    #pragma unroll
    for (int r = 0; r < 4; r++) {
        float4v* __restrict__ dst = (float4v*)(out + (size_t)(me + r) * D_OUT);
        dst[lane] = e0[r];
        if (tail) dst[64 + lane] = e1[r];
    }
#undef STAGE_HALF
#undef PHASE1_HALF
}

// ---------- fallbacks (tiny ws): round-1 proven kernels ----------
__global__ void __launch_bounds__(256)
word_emb_kernel(const int* __restrict__ words, const float* __restrict__ W_word,
                float* __restrict__ out) {
    int wave = threadIdx.x >> 6, lane = threadIdx.x & 63;
    int m = blockIdx.x * 4 + wave;
    int idx = words[m];
    const float* __restrict__ src = W_word + (size_t)idx * D_WORDE;
    float* __restrict__ dst = out + (size_t)m * D_OUT;
    for (int j = lane; j < D_WORDE; j += 64) dst[j] = src[j];
}

__global__ void __launch_bounds__(256)
char_conv_f32_kernel(const int* __restrict__ chars, const float* __restrict__ W_char,
                     const float* __restrict__ conv_w, const float* __restrict__ conv_b,
                     float* __restrict__ out) {
    __shared__ __align__(16) float xs[D_CHARE * WLEN];
    __shared__ int ids[WLEN];
    int m = blockIdx.x, s = m >> 6, b = m & 63, tid = threadIdx.x;
    if (tid < WLEN) ids[tid] = chars[(b * SENT + s) * WLEN + tid];
    __syncthreads();
    for (int e = tid; e < D_CHARE * WLEN; e += 256) {
        int c = e >> 4, l = e & 15;
        xs[e] = W_char[ids[l] * D_CHARE + c];
    }
    __syncthreads();
    if (tid < OUT_CH) {
        float acc[NPOS];
        #pragma unroll
        for (int p = 0; p < NPOS; p++) acc[p] = 0.f;
        const float4* xs4 = (const float4*)xs;
        for (int c = 0; c < D_CHARE; c++) {
            float4 a0 = xs4[c*4+0], a1 = xs4[c*4+1], a2 = xs4[c*4+2], a3 = xs4[c*4+3];
            float xr[WLEN] = {a0.x,a0.y,a0.z,a0.w, a1.x,a1.y,a1.z,a1.w,
                              a2.x,a2.y,a2.z,a2.w, a3.x,a3.y,a3.z,a3.w};
            #pragma unroll
            for (int k = 0; k < KSIZE; k++) {
                float wv = conv_w[tid * (D_CHARE * KSIZE) + c * KSIZE + k];
                #pragma unroll
                for (int p = 0; p < NPOS; p++) acc[p] = fmaf(wv, xr[p + k], acc[p]);
            }
        }
        float mx = acc[0];
        #pragma unroll
        for (int p = 1; p < NPOS; p++) mx = fmaxf(mx, acc[p]);
        out[(size_t)m * D_OUT + D_WORDE + tid] = mx + conv_b[tid];
    }
}

extern "C" void kernel_launch(void* const* d_in, const int* in_sizes, int n_in,
                              void* d_out, int out_size, void* d_ws, size_t ws_size,
                              hipStream_t stream) {
    const int*   words  = (const int*)d_in[0];
    const int*   chars  = (const int*)d_in[1];
    const float* W_word = (const float*)d_in[2];
    const float* W_char = (const float*)d_in[3];
    const float* conv_w = (const float*)d_in[4];
    const float* conv_b = (const float*)d_in[5];
    float* out = (float*)d_out;

    if (ws_size >= WS_NEED) {
        ushort* ws = (ushort*)d_ws;
        hipLaunchKernelGGL(prep_kernel,
                           dim3((CHARP_U16 + WO_U16 + 255) / 256), dim3(256), 0, stream,
                           W_char, conv_w, conv_b, ws);
        hipLaunchKernelGGL(fused_kernel, dim3(CONV_BLOCKS), dim3(256), 0, stream,
                           words, chars, W_word, ws, out);
    } else {
        hipLaunchKernelGGL(word_emb_kernel, dim3(NWORDS / 4), dim3(256), 0, stream,
                           words, W_word, out);
        hipLaunchKernelGGL(char_conv_f32_kernel, dim3(NWORDS), dim3(256), 0, stream,
                           chars, W_char, conv_w, conv_b, out);
    }
}